// Round 2
// baseline (4847.416 us; speedup 1.0000x reference)
//
#include <hip/hip_runtime.h>
#include <math.h>

// Problem constants: B=8192, S=2TX=64, F=65, HID=128, 3H=384, DIMZ=64, DIRS=2
// GD_STEP=1e-6 (two_step=2e-6), GD_ITERS=10, BN_EPS=1e-5

__device__ __forceinline__ void fma4(float4& c, float a, const float4 w) {
  c.x += a*w.x; c.y += a*w.y; c.z += a*w.z; c.w += a*w.w;
}
__device__ __forceinline__ float vget(const float4& v, int i) { return ((const float*)&v)[i]; }

// ---------------------------------------------------------------------------
// K1: per-batch feats = [HtH | Hty]  (B,64,65) + BN stat partials (spaced atomics)
// ---------------------------------------------------------------------------
__global__ __launch_bounds__(256) void k_feats(
    const float* __restrict__ Hm, const float* __restrict__ y,
    float* __restrict__ feats, float* __restrict__ bnacc)
{
  __shared__ __align__(16) float Hl[64][68];
  __shared__ float yl[64];
  __shared__ float s1[64], s2[64];
  const int b = blockIdx.x;
  const int tid = threadIdx.x;
  const float* Hb = Hm + (size_t)b*4096;
  for (int i = tid; i < 4096; i += 256) Hl[i>>6][i&63] = Hb[i];
  if (tid < 64) { yl[tid] = y[b*64+tid]; s1[tid] = 0.f; s2[tid] = 0.f; }
  __syncthreads();

  float* fb = feats + (size_t)b*4160;
  if (tid < 64) {                       // Hty column (f=64)
    float acc = 0.f;
    for (int r = 0; r < 64; ++r) acc += Hl[r][tid]*yl[r];
    fb[tid*65+64] = acc;
    atomicAdd(&s1[tid], acc);
    atomicAdd(&s2[tid], acc*acc);
  }
  // HtH: 4x4 register tile per thread
  const int tg = tid & 15, ug = tid >> 4;
  float4 acc[4];
  acc[0]=acc[1]=acc[2]=acc[3]=make_float4(0.f,0.f,0.f,0.f);
  for (int r = 0; r < 64; ++r) {
    const float4 tv = *(const float4*)&Hl[r][4*tg];
    const float4 uv = *(const float4*)&Hl[r][4*ug];
    #pragma unroll
    for (int tt=0;tt<4;++tt) fma4(acc[tt], vget(tv,tt), uv);
  }
  #pragma unroll
  for (int tt=0;tt<4;++tt) {
    const int t = 4*tg+tt;
    float sv=0.f, sq=0.f;
    #pragma unroll
    for (int uu=0;uu<4;++uu) {
      const float v = vget(acc[tt],uu);
      fb[t*65 + 4*ug + uu] = v;
      sv += v; sq += v*v;
    }
    sv += __shfl_down(sv,32); sq += __shfl_down(sq,32);
    sv += __shfl_down(sv,16); sq += __shfl_down(sq,16);
    if ((tid & 63) < 16) { atomicAdd(&s1[t], sv); atomicAdd(&s2[t], sq); }
  }
  __syncthreads();
  if (tid < 64) {
    atomicAdd(&bnacc[tid*16],      s1[tid]);
    atomicAdd(&bnacc[(64+tid)*16], s2[tid]);
  }
}

// ---------------------------------------------------------------------------
// K2a: BN finalize -> a[t]=gamma/sqrt(var+eps), c[t]=beta-mu*a
// ---------------------------------------------------------------------------
__global__ void k_bnfin(const float* __restrict__ bnacc, const float* __restrict__ gam,
                        const float* __restrict__ bet, float* __restrict__ bnac)
{
  const int t = threadIdx.x;
  if (t < 64) {
    const float inv = 1.f/532480.f;           // B*F = 8192*65
    const float mu  = bnacc[t*16]*inv;
    const float var = bnacc[(64+t)*16]*inv - mu*mu;
    const float a = gam[t]*rsqrtf(var + 1e-5f);
    bnac[t] = a;
    bnac[64+t] = bet[t] - mu*a;
  }
}

// ---------------------------------------------------------------------------
// K2b: weight transposes (k-major) + wih row sums
// wiht[d][k=f][g], whht[d][k=j_src][g], wxt/wzt[d][k=j][z]
// ---------------------------------------------------------------------------
__global__ __launch_bounds__(256) void k_prep(
    const float* __restrict__ wih, const float* __restrict__ whh,
    const float* __restrict__ Wz, const float* __restrict__ Wx,
    float* __restrict__ wiht, float* __restrict__ whht,
    float* __restrict__ wzt, float* __restrict__ wxt, float* __restrict__ rowsum)
{
  const int i = blockIdx.x*256 + threadIdx.x;
  if (i < 49920) { const int d=i/24960, r=i%24960, f=r/384, g=r%384;
                   wiht[i] = wih[d*24960 + g*65 + f]; }
  if (i < 98304) { const int d=i/49152, r=i%49152, j=r/384, g=r%384;
                   whht[i] = whh[d*49152 + g*128 + j]; }
  if (i < 16384) { const int d=i/8192, r=i%8192, j=r/64, z=r%64;
                   wzt[i] = Wz[z*256 + d*128 + j];
                   wxt[i] = Wx[z*256 + d*128 + j]; }
  if (i < 768)   { const int d=i/384, g=i%384; float s=0.f;
                   for (int f=0; f<65; ++f) s += wih[d*24960 + g*65 + f];
                   rowsum[i] = s; }
}

// ---------------------------------------------------------------------------
// K3: bidirectional GRU scan. lane = batch, wave = j-slice.
// Block: 1024 threads (16 waves) x 64-batch tile x one dir. Grid = 256.
// Weights are wave-uniform loads (16B/inst, not 512B). LDS rows are odd-pitch
// [b][k] so all lane-indexed accesses are <=2-way (free).
// ---------------------------------------------------------------------------
__global__ __launch_bounds__(1024, 4) void k_scan(
    const float* __restrict__ feats, const float* __restrict__ xraw,
    const float* __restrict__ wiht, const float* __restrict__ whht,
    const float* __restrict__ wxtw, const float* __restrict__ wztw,
    const float* __restrict__ bih, const float* __restrict__ bhh,
    const float* __restrict__ rowsum, const float* __restrict__ bnac,
    float* __restrict__ wx_out, float* __restrict__ z0_out)
{
  __shared__ float Fl[64*65];     // [b][f], pitch 65 (odd). Reused as Fl2[z][b] pitch 65.
  __shared__ float hl[64*129];    // [b][j], pitch 129 (odd)
  __shared__ float RS[384], BI[384], BH[384];

  const int tid = threadIdx.x;
  const int b   = tid & 63;                                   // lane = batch
  const int w   = __builtin_amdgcn_readfirstlane(tid >> 6);   // wave 0..15
  const int blk = blockIdx.x;
  const int tile = blk >> 1, d = blk & 1;
  const int b0 = tile * 64;

  const float* wihtd = wiht + d*24960;   // [k=f][g] g = gate*128 + j
  const float* whhtd = whht + d*49152;   // [k=j2][g]
  const float* wxtd  = wxtw + d*8192;    // [k=j][z]
  const float* wztd  = wztw + d*8192;
  float* wxo = wx_out + (size_t)d * (8192ull*4096ull);
  float* z0o = z0_out + (size_t)d * (8192ull*64ull);

  for (int i = tid; i < 384; i += 1024) {
    RS[i] = rowsum[d*384+i]; BI[i] = bih[d*384+i]; BH[i] = bhh[d*384+i];
  }
  for (int i = tid; i < 64*129; i += 1024) hl[i] = 0.f;

  const int j0  = w * 8;          // this wave's hidden-unit slice [j0, j0+8)
  const int pw  = w & 7;          // projection col block
  const int pz0 = pw * 8;
  const bool is_wz = (w >= 8);
  const float* Wp = (is_wz ? wztd : wxtd) + pz0;

  float h[8], z0a[8];
  #pragma unroll
  for (int q=0;q<8;++q) { h[q]=0.f; z0a[q]=0.f; }

  for (int it = 0; it < 64; ++it) {
    const int s = d ? (63-it) : it;
    const float a_s = bnac[s], c_s = bnac[64+s];

    __syncthreads();                        // B0: prev epilogue's Fl reads done
    #pragma unroll
    for (int r = 0; r < 4; ++r) {           // stage Fl rows 4w..4w+3 (coalesced)
      const int bb = 4*w + r;
      const float* src = feats + (size_t)(b0+bb)*4160 + s*65;
      Fl[bb*65 + b] = a_s * src[b];
      if (b == 0) Fl[bb*65 + 64] = a_s * src[64];
    }
    __syncthreads();                        // B1: Fl visible

    float aR[8], aZ[8], aNx[8], aNh[8];
    #pragma unroll
    for (int q=0;q<8;++q) { aR[q]=0.f; aZ[q]=0.f; aNx[q]=0.f; aNh[q]=0.f; }

    #pragma unroll 4
    for (int k = 0; k < 65; ++k) {          // input transform (K=65)
      const float av = Fl[b*65 + k];
      const float* wr = wihtd + k*384 + j0;
      const float4 r0 = *(const float4*)(wr);
      const float4 r1 = *(const float4*)(wr+4);
      const float4 z0v = *(const float4*)(wr+128);
      const float4 z1v = *(const float4*)(wr+132);
      const float4 n0 = *(const float4*)(wr+256);
      const float4 n1 = *(const float4*)(wr+260);
      aR[0]+=av*r0.x; aR[1]+=av*r0.y; aR[2]+=av*r0.z; aR[3]+=av*r0.w;
      aR[4]+=av*r1.x; aR[5]+=av*r1.y; aR[6]+=av*r1.z; aR[7]+=av*r1.w;
      aZ[0]+=av*z0v.x; aZ[1]+=av*z0v.y; aZ[2]+=av*z0v.z; aZ[3]+=av*z0v.w;
      aZ[4]+=av*z1v.x; aZ[5]+=av*z1v.y; aZ[6]+=av*z1v.z; aZ[7]+=av*z1v.w;
      aNx[0]+=av*n0.x; aNx[1]+=av*n0.y; aNx[2]+=av*n0.z; aNx[3]+=av*n0.w;
      aNx[4]+=av*n1.x; aNx[5]+=av*n1.y; aNx[6]+=av*n1.z; aNx[7]+=av*n1.w;
    }
    #pragma unroll 4
    for (int k = 0; k < 128; ++k) {         // recurrent (K=128)
      const float av = hl[b*129 + k];
      const float* wr = whhtd + k*384 + j0;
      const float4 r0 = *(const float4*)(wr);
      const float4 r1 = *(const float4*)(wr+4);
      const float4 z0v = *(const float4*)(wr+128);
      const float4 z1v = *(const float4*)(wr+132);
      const float4 n0 = *(const float4*)(wr+256);
      const float4 n1 = *(const float4*)(wr+260);
      aR[0]+=av*r0.x; aR[1]+=av*r0.y; aR[2]+=av*r0.z; aR[3]+=av*r0.w;
      aR[4]+=av*r1.x; aR[5]+=av*r1.y; aR[6]+=av*r1.z; aR[7]+=av*r1.w;
      aZ[0]+=av*z0v.x; aZ[1]+=av*z0v.y; aZ[2]+=av*z0v.z; aZ[3]+=av*z0v.w;
      aZ[4]+=av*z1v.x; aZ[5]+=av*z1v.y; aZ[6]+=av*z1v.z; aZ[7]+=av*z1v.w;
      aNh[0]+=av*n0.x; aNh[1]+=av*n0.y; aNh[2]+=av*n0.z; aNh[3]+=av*n0.w;
      aNh[4]+=av*n1.x; aNh[5]+=av*n1.y; aNh[6]+=av*n1.z; aNh[7]+=av*n1.w;
    }
    // gates (thread-local): r=sig(.) z=sig(.) n=tanh(xn + r*hn)
    #pragma unroll
    for (int q=0;q<8;++q) {
      const int j = j0 + q;
      const float cr  = c_s*RS[j]     + BI[j]     + BH[j];
      const float cz  = c_s*RS[128+j] + BI[128+j] + BH[128+j];
      const float cn  = c_s*RS[256+j] + BI[256+j];
      const float bhn = BH[256+j];
      const float r = 1.f/(1.f + __expf(-(aR[q] + cr)));
      const float z = 1.f/(1.f + __expf(-(aZ[q] + cz)));
      const float pre = aNx[q] + cn + r*(aNh[q] + bhn);
      const float ax = fabsf(pre);
      const float e  = __expf(-2.f*ax);
      const float n  = copysignf((1.f-e)/(1.f+e), pre);
      h[q] = (1.f - z)*n + z*h[q];
    }
    __syncthreads();                        // B2: all reads of old h done
    #pragma unroll
    for (int q=0;q<8;++q) hl[b*129 + j0 + q] = h[q];
    __syncthreads();                        // B3: new h visible

    // projections: waves 0-7 -> w_x cols, waves 8-15 -> w_z cols (z0 accum)
    float pv[8];
    #pragma unroll
    for (int q=0;q<8;++q) pv[q]=0.f;
    #pragma unroll 4
    for (int k = 0; k < 128; ++k) {
      const float hv = hl[b*129 + k];
      const float4 w0 = *(const float4*)(Wp + k*64);
      const float4 w1 = *(const float4*)(Wp + k*64 + 4);
      pv[0]+=hv*w0.x; pv[1]+=hv*w0.y; pv[2]+=hv*w0.z; pv[3]+=hv*w0.w;
      pv[4]+=hv*w1.x; pv[5]+=hv*w1.y; pv[6]+=hv*w1.z; pv[7]+=hv*w1.w;
    }
    if (!is_wz) {
      #pragma unroll
      for (int q=0;q<8;++q) Fl[(pz0+q)*65 + b] = pv[q];   // Fl2[z][b]
    } else {
      const float xh = 2.f*xraw[(b0+b)*64 + s] - 3.f;     // 2x - 2^RATE + 1
      #pragma unroll
      for (int q=0;q<8;++q) z0a[q] += xh*pv[q];
    }
    __syncthreads();                        // B4: Fl2 visible
    #pragma unroll
    for (int i2 = tid; i2 < 4096; i2 += 1024) {           // coalesced wx store
      const int bb = i2 >> 6, z = i2 & 63;
      wxo[((size_t)(b0+bb)*64 + s)*64 + z] = Fl[z*65 + bb];
    }
  }
  if (is_wz) {
    #pragma unroll
    for (int q=0;q<8;++q) z0o[(size_t)(b0+b)*64 + pz0 + q] = z0a[q];
  }
}

// ---------------------------------------------------------------------------
// K4: per-batch GD loop + output:  whhw = wx^T (HtH wx); 10 iters; out = wx z
// ---------------------------------------------------------------------------
__global__ __launch_bounds__(256) void k_gd(
    const float* __restrict__ feats, const float* __restrict__ wxf, const float* __restrict__ wxb,
    const float* __restrict__ z0f, const float* __restrict__ z0b, float* __restrict__ out)
{
  __shared__ __align__(16) float wx[64][68];
  __shared__ __align__(16) float t1[64][68];
  __shared__ __align__(16) float ww[64][68];
  __shared__ float hty[64], wh[64], zv[64];
  const int b = blockIdx.x;
  const int tid = threadIdx.x;
  const float* fb = feats + (size_t)b*4160;
  for (int i = tid; i < 4096; i += 256)
    wx[i>>6][i&63] = wxf[(size_t)b*4096 + i] + wxb[(size_t)b*4096 + i];
  if (tid < 64) hty[tid] = fb[tid*65+64];
  __syncthreads();
  const int zq = tid & 15, tq = tid >> 4;
  #pragma unroll
  for (int tt=0; tt<4; ++tt) {                 // t1 = HtH @ wx
    const int t = 4*tq + tt;
    const float* hr = fb + t*65;
    float4 a = make_float4(0.f,0.f,0.f,0.f);
    for (int u=0; u<64; ++u) fma4(a, hr[u], *(const float4*)&wx[u][4*zq]);
    *(float4*)&t1[t][4*zq] = a;
  }
  __syncthreads();
  #pragma unroll
  for (int ii=0; ii<4; ++ii) {                 // ww = wx^T @ t1
    const int zi = 4*tq + ii;
    float4 a = make_float4(0.f,0.f,0.f,0.f);
    for (int t=0; t<64; ++t) fma4(a, wx[t][zi], *(const float4*)&t1[t][4*zq]);
    *(float4*)&ww[zi][4*zq] = a;
  }
  if (tid < 64) {
    float acc = 0.f;
    for (int t=0;t<64;++t) acc += wx[t][tid]*hty[t];
    wh[tid] = acc;
    zv[tid] = z0f[(size_t)b*64+tid] + z0b[(size_t)b*64+tid];
  }
  __syncthreads();
  for (int itr=0; itr<10; ++itr) {             // z += 2e-6*(wxt_hty - ww@z)
    float nz = 0.f;
    if (tid < 64) {
      float mv = 0.f;
      for (int k2=0;k2<64;++k2) mv += ww[tid][k2]*zv[k2];
      nz = zv[tid] + 2e-6f*(wh[tid] - mv);
    }
    __syncthreads();
    if (tid < 64) zv[tid] = nz;
    __syncthreads();
  }
  if (tid < 64) {
    float o = 0.f;
    for (int z2=0;z2<64;++z2) o += wx[tid][z2]*zv[z2];
    out[(size_t)b*64 + tid] = o;
  }
}

// ---------------------------------------------------------------------------
extern "C" void kernel_launch(void* const* d_in, const int* in_sizes, int n_in,
                              void* d_out, int out_size, void* d_ws, size_t ws_size,
                              hipStream_t stream)
{
  const float* y    = (const float*)d_in[0];
  const float* Hm   = (const float*)d_in[1];
  const float* xraw = (const float*)d_in[2];
  const float* wih  = (const float*)d_in[3];
  const float* whh  = (const float*)d_in[4];
  const float* bih  = (const float*)d_in[5];
  const float* bhh  = (const float*)d_in[6];
  const float* Wz   = (const float*)d_in[7];
  const float* Wx   = (const float*)d_in[8];
  const float* gam  = (const float*)d_in[9];
  const float* bet  = (const float*)d_in[10];
  float* out = (float*)d_out;
  float* ws  = (float*)d_ws;

  float* feats = ws;                       // 8192*64*65   = 34,078,720
  float* wxf   = feats + 34078720ull;      // 33,554,432
  float* wxb   = wxf   + 33554432ull;      // 33,554,432
  float* z0f   = wxb   + 33554432ull;      // 524,288
  float* z0b   = z0f   + 524288ull;        // 524,288
  float* wiht  = z0b   + 524288ull;        // 49,920
  float* whht  = wiht  + 49920ull;         // 98,304
  float* wzt   = whht  + 98304ull;         // 16,384
  float* wxt   = wzt   + 16384ull;         // 16,384
  float* rows  = wxt   + 16384ull;         // 768
  float* bnacc = rows  + 768ull;           // 2,048 (spaced x16)
  float* bnac  = bnacc + 2048ull;          // 128

  hipMemsetAsync(bnacc, 0, 2048*sizeof(float), stream);
  k_feats<<<8192, 256, 0, stream>>>(Hm, y, feats, bnacc);
  k_prep <<<384, 256, 0, stream>>>(wih, whh, Wz, Wx, wiht, whht, wzt, wxt, rows);
  k_bnfin<<<1, 64, 0, stream>>>(bnacc, gam, bet, bnac);
  k_scan <<<256, 1024, 0, stream>>>(feats, xraw, wiht, whht, wxt, wzt,
                                    bih, bhh, rows, bnac, wxf, z0f);
  k_gd   <<<8192, 256, 0, stream>>>(feats, wxf, wxb, z0f, z0b, out);
}

// Round 3
// 4785.987 us; speedup vs baseline: 1.0128x; 1.0128x over previous
//
#include <hip/hip_runtime.h>
#include <math.h>

// Problem constants: B=8192, S=2TX=64, F=65, HID=128, 3H=384, DIMZ=64, DIRS=2
// GD_STEP=1e-6 (two_step=2e-6), GD_ITERS=10, BN_EPS=1e-5

typedef __attribute__((ext_vector_type(8))) short s8v;   // 8 x bf16 (MFMA A/B frag)
typedef __attribute__((ext_vector_type(4))) float f4v;   // MFMA C/D frag

__device__ __forceinline__ short f2bf(float x) {         // RNE float->bf16
  unsigned u = __float_as_uint(x);
  u += 0x7fffu + ((u >> 16) & 1u);
  return (short)(u >> 16);
}
__device__ __forceinline__ float bf2f(short h) {
  return __uint_as_float(((unsigned)(unsigned short)h) << 16);
}
__device__ __forceinline__ void fma4(float4& c, float a, const float4 w) {
  c.x += a*w.x; c.y += a*w.y; c.z += a*w.z; c.w += a*w.w;
}
__device__ __forceinline__ float vget(const float4& v, int i) { return ((const float*)&v)[i]; }

// ---------------------------------------------------------------------------
// K1: per-batch feats = [HtH | Hty]  (B,64,65) + BN stat partials
// ---------------------------------------------------------------------------
__global__ __launch_bounds__(256) void k_feats(
    const float* __restrict__ Hm, const float* __restrict__ y,
    float* __restrict__ feats, float* __restrict__ bnacc)
{
  __shared__ __align__(16) float Hl[64][68];
  __shared__ float yl[64];
  __shared__ float s1[64], s2[64];
  const int b = blockIdx.x;
  const int tid = threadIdx.x;
  const float* Hb = Hm + (size_t)b*4096;
  for (int i = tid; i < 4096; i += 256) Hl[i>>6][i&63] = Hb[i];
  if (tid < 64) { yl[tid] = y[b*64+tid]; s1[tid] = 0.f; s2[tid] = 0.f; }
  __syncthreads();

  float* fb = feats + (size_t)b*4160;
  if (tid < 64) {                       // Hty column (f=64)
    float acc = 0.f;
    for (int r = 0; r < 64; ++r) acc += Hl[r][tid]*yl[r];
    fb[tid*65+64] = acc;
    atomicAdd(&s1[tid], acc);
    atomicAdd(&s2[tid], acc*acc);
  }
  const int tg = tid & 15, ug = tid >> 4;
  float4 acc[4];
  acc[0]=acc[1]=acc[2]=acc[3]=make_float4(0.f,0.f,0.f,0.f);
  for (int r = 0; r < 64; ++r) {
    const float4 tv = *(const float4*)&Hl[r][4*tg];
    const float4 uv = *(const float4*)&Hl[r][4*ug];
    #pragma unroll
    for (int tt=0;tt<4;++tt) fma4(acc[tt], vget(tv,tt), uv);
  }
  #pragma unroll
  for (int tt=0;tt<4;++tt) {
    const int t = 4*tg+tt;
    float sv=0.f, sq=0.f;
    #pragma unroll
    for (int uu=0;uu<4;++uu) {
      const float v = vget(acc[tt],uu);
      fb[t*65 + 4*ug + uu] = v;
      sv += v; sq += v*v;
    }
    sv += __shfl_down(sv,32); sq += __shfl_down(sq,32);
    sv += __shfl_down(sv,16); sq += __shfl_down(sq,16);
    if ((tid & 63) < 16) { atomicAdd(&s1[t], sv); atomicAdd(&s2[t], sq); }
  }
  __syncthreads();
  if (tid < 64) {
    atomicAdd(&bnacc[tid*16],      s1[tid]);
    atomicAdd(&bnacc[(64+tid)*16], s2[tid]);
  }
}

// ---------------------------------------------------------------------------
// K2a: BN finalize -> a[t]=gamma/sqrt(var+eps), c[t]=beta-mu*a
// ---------------------------------------------------------------------------
__global__ void k_bnfin(const float* __restrict__ bnacc, const float* __restrict__ gam,
                        const float* __restrict__ bet, float* __restrict__ bnac)
{
  const int t = threadIdx.x;
  if (t < 64) {
    const float inv = 1.f/532480.f;           // B*F = 8192*65
    const float mu  = bnacc[t*16]*inv;
    const float var = bnacc[(64+t)*16]*inv - mu*mu;
    const float a = gam[t]*rsqrtf(var + 1e-5f);
    bnac[t] = a;
    bnac[64+t] = bet[t] - mu*a;
  }
}

// ---------------------------------------------------------------------------
// K2b: build split-bf16 weight images in MFMA B-fragment order + wih row sums
// Wg:  gate weights [d][sp][nt(24)][kt(6)][512]  (k: 0..63=f(wih), 64..191=j(whh))
// W2g: proj weights [d][sp][nt2(8)][kt(4)][512]  (n2: 0..63=Wx row, 64..127=Wz row)
// frag chunk: lane holds B[k=kt*32+(lane>>4)*8+i][n=nt*16+(lane&15)], i=0..7
// ---------------------------------------------------------------------------
__global__ __launch_bounds__(256) void k_prep(
    const float* __restrict__ wih, const float* __restrict__ whh,
    const float* __restrict__ Wz, const float* __restrict__ Wx,
    short* __restrict__ Wg, short* __restrict__ W2g, float* __restrict__ rowsum)
{
  const int i = blockIdx.x*256 + threadIdx.x;
  if (i < 294912) {
    const int dd = i / 147456, r = i % 147456;
    const int sp = r / 73728, r2 = r % 73728;
    const int chunk = r2 / 512, e = r2 % 512;
    const int lane = e >> 3, ii = e & 7;
    const int nt = chunk / 6, kt = chunk % 6;
    const int n = nt*16 + (lane & 15);
    const int k = kt*32 + (lane >> 4)*8 + ii;
    const float v = (k < 64) ? wih[dd*24960 + n*65 + k]
                             : whh[dd*49152 + n*128 + (k - 64)];
    const short hi = f2bf(v);
    Wg[i] = sp ? f2bf(v - bf2f(hi)) : hi;
  } else if (i < 360448) {
    const int t = i - 294912;
    const int dd = t / 32768, r = t % 32768;
    const int sp = r / 16384, r2 = r % 16384;
    const int chunk = r2 / 512, e = r2 % 512;
    const int lane = e >> 3, ii = e & 7;
    const int nt2 = chunk / 4, kt = chunk % 4;
    const int n2 = nt2*16 + (lane & 15);
    const int k = kt*32 + (lane >> 4)*8 + ii;
    const float v = (n2 < 64) ? Wx[n2*256 + dd*128 + k]
                              : Wz[(n2 - 64)*256 + dd*128 + k];
    const short hi = f2bf(v);
    W2g[t] = sp ? f2bf(v - bf2f(hi)) : hi;
  } else if (i < 361216) {
    const int t = i - 360448;
    const int dd = t / 384, g = t % 384;
    float ssum = 0.f;
    for (int f = 0; f < 65; ++f) ssum += wih[dd*24960 + g*65 + f];
    rowsum[t] = ssum;
  }
}

// ---------------------------------------------------------------------------
// K3: bidirectional GRU scan on MFMA (16x16x32 bf16, 2-way split, 3 passes).
// Block = 64 batches x one dir, 512 thr (8 waves = 2 mh x 4 nq).
// Per step: gate GEMM C[64x384] = [a_s*feats_s | h] @ Wg (+exact fp32 rank-1
// for the f=64 Hty column), gates -> h, h split hi/lo into LDS A-frag layout,
// proj GEMM [wx|wz] = h @ W2. h A-frags persist in regs across steps.
// ---------------------------------------------------------------------------
__global__ __launch_bounds__(512, 2) void k_scan(
    const float* __restrict__ feats, const float* __restrict__ xraw,
    const short* __restrict__ Wg, const short* __restrict__ W2g,
    const float* __restrict__ bih, const float* __restrict__ bhh,
    const float* __restrict__ rowsum, const float* __restrict__ bnac,
    const float* __restrict__ wih,
    float* __restrict__ wx_out, float* __restrict__ z0_out)
{
  __shared__ __align__(16) short Ax[8192];    // [sp][mt(4)][kt(2)][512]
  __shared__ __align__(16) short Ah[16384];   // [sp][mt(4)][kt(4)][512]

  const int tid = threadIdx.x;
  const int l   = tid & 63;
  const int w   = __builtin_amdgcn_readfirstlane(tid >> 6);
  const int nq  = w & 3, mh = w >> 2;
  const int T   = blockIdx.x >> 1, d = blockIdx.x & 1;
  const int b0  = T * 64;
  const int l15 = l & 15, lq = l >> 4;
  const int zb  = 16*nq + l15;

  const short* Wgd = Wg  + d*147456;
  const short* W2d = W2g + d*32768;
  float* wxo = wx_out + (size_t)d * (8192ull*4096ull);
  float* z0o = z0_out + (size_t)d * (8192ull*64ull);

  // per-lane gate constants (j = zb + 64*ntr)
  float cK[2][7], w64v[6];
  #pragma unroll
  for (int ntr = 0; ntr < 2; ++ntr) {
    const int j = zb + 64*ntr;
    cK[ntr][0] = rowsum[d*384 + j];
    cK[ntr][1] = bih[d*384 + j] + bhh[d*384 + j];
    cK[ntr][2] = rowsum[d*384 + 128 + j];
    cK[ntr][3] = bih[d*384 + 128 + j] + bhh[d*384 + 128 + j];
    cK[ntr][4] = rowsum[d*384 + 256 + j];
    cK[ntr][5] = bih[d*384 + 256 + j];
    cK[ntr][6] = bhh[d*384 + 256 + j];
  }
  #pragma unroll
  for (int ntIdx = 0; ntIdx < 6; ++ntIdx) {
    const int n = 16*(nq + 4*ntIdx) + l15;
    w64v[ntIdx] = wih[d*24960 + n*65 + 64];   // f=64 column (rank-1 part)
  }
  // batch index of each C row this lane owns
  int bidx[2][4];
  #pragma unroll
  for (int mtp = 0; mtp < 2; ++mtp)
    #pragma unroll
    for (int r = 0; r < 4; ++r)
      bidx[mtp][r] = b0 + (2*mh + mtp)*16 + lq*4 + r;

  // Ax frag-build decode (8 elems/thread): e2 = tid+512*t
  int fb[8];
  #pragma unroll
  for (int t = 0; t < 8; ++t) {
    const int e2 = tid + 512*t;
    const int c  = e2 >> 9, q = (e2 >> 7) & 3, m16 = (e2 >> 3) & 15, ii = e2 & 7;
    const int mt = c >> 1, kt = c & 1;
    fb[t] = (b0 + mt*16 + m16)*4160 + kt*32 + q*8 + ii;
  }
  // h-write base addrs (value h[b][j] -> A-frag position)
  int hwa[2][2];
  #pragma unroll
  for (int ntr = 0; ntr < 2; ++ntr) {
    const int jj = zb + 64*ntr;
    const int kth = jj >> 5, qh = (jj >> 3) & 3, ih = jj & 7;
    #pragma unroll
    for (int mtp = 0; mtp < 2; ++mtp)
      hwa[ntr][mtp] = (((2*mh + mtp)*4 + kth)*512) + qh*128 + (lq*4)*8 + ih;
  }

  f4v hprev[2][2], z0a[2];
  s8v Ahh[2][4], Ahl2[2][4];
  #pragma unroll
  for (int a = 0; a < 2; ++a) {
    z0a[a] = (f4v)0.f;
    #pragma unroll
    for (int c = 0; c < 2; ++c) hprev[a][c] = (f4v)0.f;
    #pragma unroll
    for (int c = 0; c < 4; ++c) { Ahh[a][c] = (s8v)0; Ahl2[a][c] = (s8v)0; }
  }

  for (int it = 0; it < 64; ++it) {
    const int s = d ? 63 - it : it;
    const float a_s = bnac[s], c_s = bnac[64 + s];

    // build Ax frags (hi at [e2], lo at [4096+e2])
    #pragma unroll
    for (int t = 0; t < 8; ++t) {
      const float v = a_s * feats[(size_t)(fb[t] + s*65)];
      const short hi = f2bf(v);
      Ax[tid + 512*t] = hi;
      Ax[4096 + tid + 512*t] = f2bf(v - bf2f(hi));
    }
    // Hty values for exact fp32 rank-1 (f=64)
    f4v a64[2];
    #pragma unroll
    for (int mtp = 0; mtp < 2; ++mtp)
      #pragma unroll
      for (int r = 0; r < 4; ++r)
        a64[mtp][r] = a_s * feats[(size_t)bidx[mtp][r]*4160 + s*65 + 64];

    __syncthreads();   // B: Ax ready; prior-step Ah readers all done

    f4v C[6][2], Cnh[2][2];
    #pragma unroll
    for (int a2 = 0; a2 < 6; ++a2) { C[a2][0] = (f4v)0.f; C[a2][1] = (f4v)0.f; }
    Cnh[0][0] = (f4v)0.f; Cnh[0][1] = (f4v)0.f;
    Cnh[1][0] = (f4v)0.f; Cnh[1][1] = (f4v)0.f;

    {   // passes 0 (Ahi*Bhi) and 1 (Ahi*Blo)
      s8v Axh[2][2];
      #pragma unroll
      for (int mtp = 0; mtp < 2; ++mtp)
        #pragma unroll
        for (int kt = 0; kt < 2; ++kt)
          Axh[mtp][kt] = *(const s8v*)&Ax[((2*mh + mtp)*2 + kt)*512 + l*8];
      #pragma unroll
      for (int p = 0; p < 2; ++p)
        #pragma unroll
        for (int ntIdx = 0; ntIdx < 6; ++ntIdx) {
          const int nt = nq + 4*ntIdx;
          #pragma unroll
          for (int kt = 0; kt < 6; ++kt) {
            const s8v bv = *(const s8v*)&Wgd[((p*24 + nt)*6 + kt)*512 + l*8];
            #pragma unroll
            for (int mtp = 0; mtp < 2; ++mtp) {
              const s8v av = (kt < 2) ? Axh[mtp][kt] : Ahh[mtp][kt-2];
              if (ntIdx < 4 || kt < 2)
                C[ntIdx][mtp] = __builtin_amdgcn_mfma_f32_16x16x32_bf16(av, bv, C[ntIdx][mtp], 0, 0, 0);
              else
                Cnh[ntIdx-4][mtp] = __builtin_amdgcn_mfma_f32_16x16x32_bf16(av, bv, Cnh[ntIdx-4][mtp], 0, 0, 0);
            }
          }
        }
    }
    {   // pass 2 (Alo*Bhi)
      s8v Axl[2][2];
      #pragma unroll
      for (int mtp = 0; mtp < 2; ++mtp)
        #pragma unroll
        for (int kt = 0; kt < 2; ++kt)
          Axl[mtp][kt] = *(const s8v*)&Ax[4096 + ((2*mh + mtp)*2 + kt)*512 + l*8];
      #pragma unroll
      for (int ntIdx = 0; ntIdx < 6; ++ntIdx) {
        const int nt = nq + 4*ntIdx;
        #pragma unroll
        for (int kt = 0; kt < 6; ++kt) {
          const s8v bv = *(const s8v*)&Wgd[(nt*6 + kt)*512 + l*8];
          #pragma unroll
          for (int mtp = 0; mtp < 2; ++mtp) {
            const s8v av = (kt < 2) ? Axl[mtp][kt] : Ahl2[mtp][kt-2];
            if (ntIdx < 4 || kt < 2)
              C[ntIdx][mtp] = __builtin_amdgcn_mfma_f32_16x16x32_bf16(av, bv, C[ntIdx][mtp], 0, 0, 0);
            else
              Cnh[ntIdx-4][mtp] = __builtin_amdgcn_mfma_f32_16x16x32_bf16(av, bv, Cnh[ntIdx-4][mtp], 0, 0, 0);
          }
        }
      }
    }
    // exact fp32 rank-1 for f=64 (Hty column)
    #pragma unroll
    for (int ntIdx = 0; ntIdx < 6; ++ntIdx)
      #pragma unroll
      for (int mtp = 0; mtp < 2; ++mtp)
        C[ntIdx][mtp] += a64[mtp] * w64v[ntIdx];

    // gates: r=sig, z=sig, n=tanh(xn + r*hn); h-update; split+write to Ah
    #pragma unroll
    for (int ntr = 0; ntr < 2; ++ntr) {
      const float cr  = c_s*cK[ntr][0] + cK[ntr][1];
      const float cz  = c_s*cK[ntr][2] + cK[ntr][3];
      const float cn  = c_s*cK[ntr][4] + cK[ntr][5];
      const float bhn = cK[ntr][6];
      #pragma unroll
      for (int mtp = 0; mtp < 2; ++mtp)
        #pragma unroll
        for (int e = 0; e < 4; ++e) {
          const float rr  = 1.f/(1.f + __expf(-(C[ntr][mtp][e] + cr)));
          const float zz  = 1.f/(1.f + __expf(-(C[2+ntr][mtp][e] + cz)));
          const float pre = C[4+ntr][mtp][e] + cn + rr*(Cnh[ntr][mtp][e] + bhn);
          const float ax2 = fabsf(pre);
          const float ee  = __expf(-2.f*ax2);
          const float nn  = copysignf((1.f - ee)/(1.f + ee), pre);
          const float hv  = (1.f - zz)*nn + zz*hprev[ntr][mtp][e];
          hprev[ntr][mtp][e] = hv;
          const short hi = f2bf(hv);
          Ah[hwa[ntr][mtp] + e*8] = hi;
          Ah[8192 + hwa[ntr][mtp] + e*8] = f2bf(hv - bf2f(hi));
        }
    }
    __syncthreads();   // C: Ah(s) complete

    // proj A-frags (also next step's recurrent A operands)
    #pragma unroll
    for (int mtp = 0; mtp < 2; ++mtp)
      #pragma unroll
      for (int kt = 0; kt < 4; ++kt) {
        const int mt = 2*mh + mtp;
        Ahh[mtp][kt]  = *(const s8v*)&Ah[(mt*4 + kt)*512 + l*8];
        Ahl2[mtp][kt] = *(const s8v*)&Ah[8192 + (mt*4 + kt)*512 + l*8];
      }
    f4v Cp[2][2];
    Cp[0][0] = (f4v)0.f; Cp[0][1] = (f4v)0.f;
    Cp[1][0] = (f4v)0.f; Cp[1][1] = (f4v)0.f;
    #pragma unroll
    for (int p = 0; p < 3; ++p) {
      const int spB = (p == 1) ? 1 : 0;
      #pragma unroll
      for (int n2 = 0; n2 < 2; ++n2) {
        const int nt2 = nq + 4*n2;
        #pragma unroll
        for (int kt = 0; kt < 4; ++kt) {
          const s8v bv = *(const s8v*)&W2d[((spB*8 + nt2)*4 + kt)*512 + l*8];
          #pragma unroll
          for (int mtp = 0; mtp < 2; ++mtp) {
            const s8v av = (p < 2) ? Ahh[mtp][kt] : Ahl2[mtp][kt];
            Cp[n2][mtp] = __builtin_amdgcn_mfma_f32_16x16x32_bf16(av, bv, Cp[n2][mtp], 0, 0, 0);
          }
        }
      }
    }
    // stores: wx (n2=0 -> Wx cols), z0 accumulate (n2=1 -> Wz cols)
    #pragma unroll
    for (int mtp = 0; mtp < 2; ++mtp) {
      #pragma unroll
      for (int r = 0; r < 4; ++r)
        wxo[(size_t)bidx[mtp][r]*4096 + s*64 + zb] = Cp[0][mtp][r];
      f4v xh;
      #pragma unroll
      for (int r = 0; r < 4; ++r)
        xh[r] = 2.f*xraw[bidx[mtp][r]*64 + s] - 3.f;   // 2x - 2^RATE + 1
      z0a[mtp] += xh * Cp[1][mtp];
    }
  }
  #pragma unroll
  for (int mtp = 0; mtp < 2; ++mtp)
    #pragma unroll
    for (int r = 0; r < 4; ++r)
      z0o[bidx[mtp][r]*64 + zb] = z0a[mtp][r];
}

// ---------------------------------------------------------------------------
// K4: per-batch GD loop + output:  whhw = wx^T (HtH wx); 10 iters; out = wx z
// ---------------------------------------------------------------------------
__global__ __launch_bounds__(256) void k_gd(
    const float* __restrict__ feats, const float* __restrict__ wxf, const float* __restrict__ wxb,
    const float* __restrict__ z0f, const float* __restrict__ z0b, float* __restrict__ out)
{
  __shared__ __align__(16) float wx[64][68];
  __shared__ __align__(16) float t1[64][68];
  __shared__ __align__(16) float ww[64][68];
  __shared__ float hty[64], wh[64], zv[64];
  const int b = blockIdx.x;
  const int tid = threadIdx.x;
  const float* fb = feats + (size_t)b*4160;
  for (int i = tid; i < 4096; i += 256)
    wx[i>>6][i&63] = wxf[(size_t)b*4096 + i] + wxb[(size_t)b*4096 + i];
  if (tid < 64) hty[tid] = fb[tid*65+64];
  __syncthreads();
  const int zq = tid & 15, tq = tid >> 4;
  #pragma unroll
  for (int tt=0; tt<4; ++tt) {                 // t1 = HtH @ wx
    const int t = 4*tq + tt;
    const float* hr = fb + t*65;
    float4 a = make_float4(0.f,0.f,0.f,0.f);
    for (int u=0; u<64; ++u) fma4(a, hr[u], *(const float4*)&wx[u][4*zq]);
    *(float4*)&t1[t][4*zq] = a;
  }
  __syncthreads();
  #pragma unroll
  for (int ii=0; ii<4; ++ii) {                 // ww = wx^T @ t1
    const int zi = 4*tq + ii;
    float4 a = make_float4(0.f,0.f,0.f,0.f);
    for (int t=0; t<64; ++t) fma4(a, wx[t][zi], *(const float4*)&t1[t][4*zq]);
    *(float4*)&ww[zi][4*zq] = a;
  }
  if (tid < 64) {
    float acc = 0.f;
    for (int t=0;t<64;++t) acc += wx[t][tid]*hty[t];
    wh[tid] = acc;
    zv[tid] = z0f[(size_t)b*64+tid] + z0b[(size_t)b*64+tid];
  }
  __syncthreads();
  for (int itr=0; itr<10; ++itr) {             // z += 2e-6*(wxt_hty - ww@z)
    float nz = 0.f;
    if (tid < 64) {
      float mv = 0.f;
      for (int k2=0;k2<64;++k2) mv += ww[tid][k2]*zv[k2];
      nz = zv[tid] + 2e-6f*(wh[tid] - mv);
    }
    __syncthreads();
    if (tid < 64) zv[tid] = nz;
    __syncthreads();
  }
  if (tid < 64) {
    float o = 0.f;
    for (int z2=0;z2<64;++z2) o += wx[tid][z2]*zv[z2];
    out[(size_t)b*64 + tid] = o;
  }
}

// ---------------------------------------------------------------------------
extern "C" void kernel_launch(void* const* d_in, const int* in_sizes, int n_in,
                              void* d_out, int out_size, void* d_ws, size_t ws_size,
                              hipStream_t stream)
{
  const float* y    = (const float*)d_in[0];
  const float* Hm   = (const float*)d_in[1];
  const float* xraw = (const float*)d_in[2];
  const float* wih  = (const float*)d_in[3];
  const float* whh  = (const float*)d_in[4];
  const float* bih  = (const float*)d_in[5];
  const float* bhh  = (const float*)d_in[6];
  const float* Wz   = (const float*)d_in[7];
  const float* Wx   = (const float*)d_in[8];
  const float* gam  = (const float*)d_in[9];
  const float* bet  = (const float*)d_in[10];
  float* out = (float*)d_out;
  float* ws  = (float*)d_ws;

  // ws layout (floats), total ~102.42M floats (~410 MB)
  float* feats = ws;                       // 34,078,720
  float* wxf   = feats + 34078720ull;      // 33,554,432
  float* wxb   = wxf   + 33554432ull;      // 33,554,432
  float* z0f   = wxb   + 33554432ull;      // 524,288
  float* z0b   = z0f   + 524288ull;        // 524,288
  float* rows  = z0b   + 524288ull;        // 768
  float* bnacc = rows  + 768ull;           // 2,048 (spaced x16)
  float* bnac  = bnacc + 2048ull;          // 128
  short* Wgs   = (short*)(bnac + 128ull);  // 294,912 shorts (147,456 f)
  short* W2gs  = (short*)(bnac + 128ull + 147456ull);  // 65,536 shorts

  hipMemsetAsync(bnacc, 0, 2048*sizeof(float), stream);
  k_feats<<<8192, 256, 0, stream>>>(Hm, y, feats, bnacc);
  k_prep <<<1412, 256, 0, stream>>>(wih, whh, Wz, Wx, Wgs, W2gs, rows);
  k_bnfin<<<1, 64, 0, stream>>>(bnacc, gam, bet, bnac);
  k_scan <<<256, 512, 0, stream>>>(feats, xraw, Wgs, W2gs,
                                   bih, bhh, rows, bnac, wih, wxf, z0f);
  k_gd   <<<8192, 256, 0, stream>>>(feats, wxf, wxb, z0f, z0b, out);
}

// Round 5
// 2106.043 us; speedup vs baseline: 2.3017x; 2.2725x over previous
//
#include <hip/hip_runtime.h>
#include <math.h>

// Problem constants: B=8192, S=2TX=64, F=65, HID=128, 3H=384, DIMZ=64, DIRS=2
// GD_STEP=1e-6 (two_step=2e-6), GD_ITERS=10, BN_EPS=1e-5

typedef __attribute__((ext_vector_type(8))) short s8v;   // 8 x bf16 (MFMA A/B frag)
typedef __attribute__((ext_vector_type(4))) float f4v;   // MFMA C/D frag

__device__ __forceinline__ short f2bf(float x) {         // RNE float->bf16
  unsigned u = __float_as_uint(x);
  u += 0x7fffu + ((u >> 16) & 1u);
  return (short)(u >> 16);
}
__device__ __forceinline__ float bf2f(short h) {
  return __uint_as_float(((unsigned)(unsigned short)h) << 16);
}
__device__ __forceinline__ void fma4(float4& c, float a, const float4 w) {
  c.x += a*w.x; c.y += a*w.y; c.z += a*w.z; c.w += a*w.w;
}
__device__ __forceinline__ float vget(const float4& v, int i) { return ((const float*)&v)[i]; }

#define MFMA(A, B, C) __builtin_amdgcn_mfma_f32_16x16x32_bf16((A), (B), (C), 0, 0, 0)

// ---------------------------------------------------------------------------
// K1: per-batch HtH -> UNSCALED split-bf16 fragX (A-frag order), htyU[s][b],
// BN stat partials. fragX elem (b,s,k): tile=b>>6, mt=(b>>4)&3, chunk kt=k>>5,
// lane=(b&15)+16*((k>>3)&3), i=k&7; hi at chunk*512+lane*8+i, lo at +4096.
// ---------------------------------------------------------------------------
__global__ __launch_bounds__(256) void k_feats(
    const float* __restrict__ Hm, const float* __restrict__ y,
    short* __restrict__ fragX, float* __restrict__ htyU, float* __restrict__ bnacc)
{
  __shared__ __align__(16) float Hl[64][68];
  __shared__ float yl[64];
  __shared__ float s1[64], s2[64];
  const int b = blockIdx.x;
  const int tid = threadIdx.x;
  const float* Hb = Hm + (size_t)b*4096;
  for (int i = tid; i < 4096; i += 256) Hl[i>>6][i&63] = Hb[i];
  if (tid < 64) { yl[tid] = y[b*64+tid]; s1[tid] = 0.f; s2[tid] = 0.f; }
  __syncthreads();

  if (tid < 64) {                       // Hty channel (f=64), unscaled, [s][b]
    float acc = 0.f;
    for (int r = 0; r < 64; ++r) acc += Hl[r][tid]*yl[r];
    htyU[tid*8192 + b] = acc;
    atomicAdd(&s1[tid], acc);
    atomicAdd(&s2[tid], acc*acc);
  }
  const int tg = tid & 15, ug = tid >> 4;
  float4 acc4[4];
  acc4[0]=acc4[1]=acc4[2]=acc4[3]=make_float4(0.f,0.f,0.f,0.f);
  for (int r = 0; r < 64; ++r) {        // HtH[t=4tg+tt][u=4ug+uu]
    const float4 tv = *(const float4*)&Hl[r][4*tg];
    const float4 uv = *(const float4*)&Hl[r][4*ug];
    #pragma unroll
    for (int tt=0;tt<4;++tt) fma4(acc4[tt], vget(tv,tt), uv);
  }
  // frag-store geometry (u = 4ug..4ug+3 -> 4 consecutive shorts in one group)
  const int mt   = (b >> 4) & 3;
  const int brow = b & 15;
  const int u0   = 4*ug;
  short* fbase = fragX + (size_t)(b >> 6)*64*8192
               + (mt*2 + (u0 >> 5))*512 + (brow + 16*((u0 >> 3) & 3))*8 + (u0 & 7);
  #pragma unroll
  for (int tt=0;tt<4;++tt) {
    const int t = 4*tg+tt;              // t == seq channel s
    float sv=0.f, sq=0.f;
    short hib[4], lob[4];
    #pragma unroll
    for (int uu=0;uu<4;++uu) {
      const float v = vget(acc4[tt],uu);
      const short hi = f2bf(v);
      hib[uu] = hi; lob[uu] = f2bf(v - bf2f(hi));
      sv += v; sq += v*v;
    }
    short* dst = fbase + (size_t)t*8192;
    *(short4*)dst          = make_short4(hib[0],hib[1],hib[2],hib[3]);
    *(short4*)(dst + 4096) = make_short4(lob[0],lob[1],lob[2],lob[3]);
    sv += __shfl_down(sv,32); sq += __shfl_down(sq,32);
    sv += __shfl_down(sv,16); sq += __shfl_down(sq,16);
    if ((tid & 63) < 16) { atomicAdd(&s1[t], sv); atomicAdd(&s2[t], sq); }
  }
  __syncthreads();
  if (tid < 64) {
    atomicAdd(&bnacc[tid*16],      s1[tid]);
    atomicAdd(&bnacc[(64+tid)*16], s2[tid]);
  }
}

// ---------------------------------------------------------------------------
// K2a: BN finalize -> a[t]=gamma/sqrt(var+eps), c[t]=beta-mu*a
// ---------------------------------------------------------------------------
__global__ void k_bnfin(const float* __restrict__ bnacc, const float* __restrict__ gam,
                        const float* __restrict__ bet, float* __restrict__ bnac)
{
  const int t = threadIdx.x;
  if (t < 64) {
    const float inv = 1.f/532480.f;           // B*F = 8192*65
    const float mu  = bnacc[t*16]*inv;
    const float var = bnacc[(64+t)*16]*inv - mu*mu;
    const float a = gam[t]*rsqrtf(var + 1e-5f);
    bnac[t] = a;
    bnac[64+t] = bet[t] - mu*a;
  }
}

// ---------------------------------------------------------------------------
// K2b: split-bf16 weight images in MFMA B-frag order + wih row sums
// Wg:  [d][sp][nt(24)][kt(6)][512]  (k: 0..63=f(wih), 64..191=j(whh))
// W2g: [d][sp][nt2(8)][kt(4)][512]  (n2: 0..63=Wx row, 64..127=Wz row)
// ---------------------------------------------------------------------------
__global__ __launch_bounds__(256) void k_prep(
    const float* __restrict__ wih, const float* __restrict__ whh,
    const float* __restrict__ Wz, const float* __restrict__ Wx,
    short* __restrict__ Wg, short* __restrict__ W2g, float* __restrict__ rowsum)
{
  const int i = blockIdx.x*256 + threadIdx.x;
  if (i < 294912) {
    const int dd = i / 147456, r = i % 147456;
    const int sp = r / 73728, r2 = r % 73728;
    const int chunk = r2 / 512, e = r2 % 512;
    const int lane = e >> 3, ii = e & 7;
    const int nt = chunk / 6, kt = chunk % 6;
    const int n = nt*16 + (lane & 15);
    const int k = kt*32 + (lane >> 4)*8 + ii;
    const float v = (k < 64) ? wih[dd*24960 + n*65 + k]
                             : whh[dd*49152 + n*128 + (k - 64)];
    const short hi = f2bf(v);
    Wg[i] = sp ? f2bf(v - bf2f(hi)) : hi;
  } else if (i < 360448) {
    const int t = i - 294912;
    const int dd = t / 32768, r = t % 32768;
    const int sp = r / 16384, r2 = r % 16384;
    const int chunk = r2 / 512, e = r2 % 512;
    const int lane = e >> 3, ii = e & 7;
    const int nt2 = chunk / 4, kt = chunk % 4;
    const int n2 = nt2*16 + (lane & 15);
    const int k = kt*32 + (lane >> 4)*8 + ii;
    const float v = (n2 < 64) ? Wx[n2*256 + dd*128 + k]
                              : Wz[(n2 - 64)*256 + dd*128 + k];
    const short hi = f2bf(v);
    W2g[t] = sp ? f2bf(v - bf2f(hi)) : hi;
  } else if (i < 361216) {
    const int t = i - 360448;
    const int dd = t / 384, g = t % 384;
    float ssum = 0.f;
    for (int f = 0; f < 65; ++f) ssum += wih[dd*24960 + g*65 + f];
    rowsum[t] = ssum;
  }
}

// ---------------------------------------------------------------------------
// K3: GRU scan, register-resident weights. Block = 64 batches x 1 dir, 8 waves.
// Wave w owns gate cols {j,128+j,256+j : j=16w+l15} + proj slice nt2=w.
// x-part and h-part accumulate separately; BN scale a_s applied in fp32
// epilogue (a_s is a per-step scalar, commutes out of the GEMM).
// ---------------------------------------------------------------------------
__global__ __launch_bounds__(512, 2) void k_scan(
    const short* __restrict__ fragX, const float* __restrict__ htyU,
    const float* __restrict__ xraw,
    const short* __restrict__ Wg, const short* __restrict__ W2g,
    const float* __restrict__ bih, const float* __restrict__ bhh,
    const float* __restrict__ rowsum, const float* __restrict__ bnac,
    const float* __restrict__ wih,
    float* __restrict__ wx_out, float* __restrict__ z0_out)
{
  __shared__ __align__(16) short Ax[8192];    // [sp][mt(4)][ktx(2)][512]
  __shared__ __align__(16) short Ah[16384];   // [sp][mt(4)][kth(4)][512]

  const int tid = threadIdx.x;
  const int l   = tid & 63;
  const int w   = __builtin_amdgcn_readfirstlane(tid >> 6);   // wave 0..7
  const int tile = blockIdx.x >> 1, d = blockIdx.x & 1;
  const int b0  = tile * 64;
  const int l15 = l & 15, lq = l >> 4;
  const int j   = 16*w + l15;                 // this lane's hidden unit

  const short* Wgd = Wg  + d*147456;
  const short* W2d = W2g + d*32768;
  float* wxo = wx_out + (size_t)d * (8192ull*4096ull);
  float* z0o = z0_out + (size_t)d * (8192ull*64ull);

  // ---- persistent weight fragments (VGPR-resident) ----
  s8v BR[6][2], BZ[6][2], BN[6][2], BP[4][2];
  #pragma unroll
  for (int kt = 0; kt < 6; ++kt)
    #pragma unroll
    for (int sp = 0; sp < 2; ++sp) {
      BR[kt][sp] = *(const s8v*)&Wgd[((sp*24 + w     )*6 + kt)*512 + l*8];
      BZ[kt][sp] = *(const s8v*)&Wgd[((sp*24 + 8 + w )*6 + kt)*512 + l*8];
      BN[kt][sp] = *(const s8v*)&Wgd[((sp*24 + 16 + w)*6 + kt)*512 + l*8];
    }
  #pragma unroll
  for (int kt = 0; kt < 4; ++kt)
    #pragma unroll
    for (int sp = 0; sp < 2; ++sp)
      BP[kt][sp] = *(const s8v*)&W2d[((sp*8 + w)*4 + kt)*512 + l*8];

  // ---- per-lane gate constants ----
  const float rsR = rowsum[d*384 + j];
  const float rsZ = rowsum[d*384 + 128 + j];
  const float rsN = rowsum[d*384 + 256 + j];
  const float KR  = bih[d*384 + j]       + bhh[d*384 + j];
  const float KZ  = bih[d*384 + 128 + j] + bhh[d*384 + 128 + j];
  const float KN  = bih[d*384 + 256 + j];
  const float BHN = bhh[d*384 + 256 + j];
  const float w64r = wih[d*24960 + j*65 + 64];          // f=64 (Hty) column
  const float w64z = wih[d*24960 + (128 + j)*65 + 64];
  const float w64n = wih[d*24960 + (256 + j)*65 + 64];

  // h-write geometry: value (m, j) -> A-frag slot
  const int hw_base = (j >> 5)*512 + ((j >> 3) & 3)*128 + (j & 7);

  for (int i = tid; i < 16384; i += 512) Ah[i] = 0;

  f4v hprev[4], z0a[4];
  #pragma unroll
  for (int mt = 0; mt < 4; ++mt) { hprev[mt] = (f4v)0.f; z0a[mt] = (f4v)0.f; }

  {   // preload Ax(s_first)
    const int s0 = d ? 63 : 0;
    const short* src = fragX + (size_t)(tile*64 + s0)*8192;
    *(float4*)((char*)Ax + tid*16)        = *(const float4*)((const char*)src + tid*16);
    *(float4*)((char*)Ax + 8192 + tid*16) = *(const float4*)((const char*)src + 8192 + tid*16);
  }
  __syncthreads();

  for (int it = 0; it < 64; ++it) {
    const int s  = d ? 63 - it : it;
    const int sn = (it < 63) ? (d ? s - 1 : s + 1) : s;

    // register-prefetch next step's Ax (latency hidden under gate GEMM)
    const short* srcn = fragX + (size_t)(tile*64 + sn)*8192;
    const float4 pf0 = *(const float4*)((const char*)srcn + tid*16);
    const float4 pf1 = *(const float4*)((const char*)srcn + 8192 + tid*16);

    const float a_s = bnac[s], c_s = bnac[64 + s];
    const float crK = c_s*rsR + KR;
    const float czK = c_s*rsZ + KZ;
    const float cnK = c_s*rsN + KN;

    // ---- gate GEMM + gates, per M-tile ----
    #pragma unroll
    for (int mt = 0; mt < 4; ++mt) {
      f4v Crx = (f4v)0.f, Czx = (f4v)0.f, Cnx = (f4v)0.f;
      f4v Crh = (f4v)0.f, Czh = (f4v)0.f, Cnh = (f4v)0.f;
      #pragma unroll
      for (int kt = 0; kt < 2; ++kt) {        // x part (K=64, unscaled)
        const s8v axh = *(const s8v*)&Ax[mt*1024 + kt*512 + l*8];
        const s8v axl = *(const s8v*)&Ax[4096 + mt*1024 + kt*512 + l*8];
        Crx = MFMA(axh, BR[kt][0], Crx); Crx = MFMA(axh, BR[kt][1], Crx); Crx = MFMA(axl, BR[kt][0], Crx);
        Czx = MFMA(axh, BZ[kt][0], Czx); Czx = MFMA(axh, BZ[kt][1], Czx); Czx = MFMA(axl, BZ[kt][0], Czx);
        Cnx = MFMA(axh, BN[kt][0], Cnx); Cnx = MFMA(axh, BN[kt][1], Cnx); Cnx = MFMA(axl, BN[kt][0], Cnx);
      }
      #pragma unroll
      for (int kh = 0; kh < 4; ++kh) {        // h part (K=128)
        const s8v ahh = *(const s8v*)&Ah[mt*2048 + kh*512 + l*8];
        const s8v ahl = *(const s8v*)&Ah[8192 + mt*2048 + kh*512 + l*8];
        const int kt = 2 + kh;
        Crh = MFMA(ahh, BR[kt][0], Crh); Crh = MFMA(ahh, BR[kt][1], Crh); Crh = MFMA(ahl, BR[kt][0], Crh);
        Czh = MFMA(ahh, BZ[kt][0], Czh); Czh = MFMA(ahh, BZ[kt][1], Czh); Czh = MFMA(ahl, BZ[kt][0], Czh);
        Cnh = MFMA(ahh, BN[kt][0], Cnh); Cnh = MFMA(ahh, BN[kt][1], Cnh); Cnh = MFMA(ahl, BN[kt][0], Cnh);
      }
      // exact fp32 rank-1 for the Hty channel (joins x-part, pre-a_s)
      f4v av;
      #pragma unroll
      for (int e = 0; e < 4; ++e) av[e] = htyU[s*8192 + b0 + mt*16 + lq*4 + e];
      Crx += av * w64r; Czx += av * w64z; Cnx += av * w64n;
      // gates: r=sig, z=sig, n=tanh(xn + r*hn); BN scale a_s applied here
      #pragma unroll
      for (int e = 0; e < 4; ++e) {
        const float rr  = 1.f/(1.f + __expf(-(a_s*Crx[e] + Crh[e] + crK)));
        const float zz  = 1.f/(1.f + __expf(-(a_s*Czx[e] + Czh[e] + czK)));
        const float pre = a_s*Cnx[e] + cnK + rr*(Cnh[e] + BHN);
        const float ax2 = fabsf(pre);
        const float ee  = __expf(-2.f*ax2);
        const float nn  = copysignf((1.f - ee)/(1.f + ee), pre);
        hprev[mt][e] = (1.f - zz)*nn + zz*hprev[mt][e];
      }
    }
    __syncthreads();   // B2: all reads of Ax(s) and Ah(s-1) complete

    // write h(s) hi/lo into Ah (A-frag layout); write prefetched Ax(s+1)
    #pragma unroll
    for (int mt = 0; mt < 4; ++mt)
      #pragma unroll
      for (int e = 0; e < 4; ++e) {
        const float hv = hprev[mt][e];
        const short hi = f2bf(hv);
        const int ad = mt*2048 + hw_base + (lq*4 + e)*8;
        Ah[ad] = hi;
        Ah[8192 + ad] = f2bf(hv - bf2f(hi));
      }
    *(float4*)((char*)Ax + tid*16)        = pf0;
    *(float4*)((char*)Ax + 8192 + tid*16) = pf1;
    __syncthreads();   // B3: Ah(s), Ax(s+1) visible

    // ---- projection: waves 0-3 -> wx cols, waves 4-7 -> wz (z0 accum) ----
    #pragma unroll
    for (int mt = 0; mt < 4; ++mt) {
      f4v Cp = (f4v)0.f;
      #pragma unroll
      for (int kt = 0; kt < 4; ++kt) {
        const s8v ahh = *(const s8v*)&Ah[mt*2048 + kt*512 + l*8];
        const s8v ahl = *(const s8v*)&Ah[8192 + mt*2048 + kt*512 + l*8];
        Cp = MFMA(ahh, BP[kt][0], Cp);
        Cp = MFMA(ahh, BP[kt][1], Cp);
        Cp = MFMA(ahl, BP[kt][0], Cp);
      }
      if (w < 4) {
        #pragma unroll
        for (int e = 0; e < 4; ++e)
          wxo[(size_t)(b0 + mt*16 + lq*4 + e)*4096 + s*64 + 16*w + l15] = Cp[e];
      } else {
        f4v xh;
        #pragma unroll
        for (int e = 0; e < 4; ++e)
          xh[e] = 2.f*xraw[(b0 + mt*16 + lq*4 + e)*64 + s] - 3.f;  // 2x-2^RATE+1
        z0a[mt] += xh * Cp;
      }
    }
  }
  if (w >= 4) {
    #pragma unroll
    for (int mt = 0; mt < 4; ++mt)
      #pragma unroll
      for (int e = 0; e < 4; ++e)
        z0o[(size_t)(b0 + mt*16 + lq*4 + e)*64 + 16*(w-4) + l15] = z0a[mt][e];
  }
}

// ---------------------------------------------------------------------------
// K4: GD loop via Gram trick: tmp=H@wx; ww=tmp^T tmp; wh=tmp^T y (no HtH).
// ---------------------------------------------------------------------------
__global__ __launch_bounds__(256) void k_gd(
    const float* __restrict__ Hm, const float* __restrict__ y,
    const float* __restrict__ wxf, const float* __restrict__ wxb,
    const float* __restrict__ z0f, const float* __restrict__ z0b,
    float* __restrict__ out)
{
  __shared__ __align__(16) float Hl[64][68];    // H[r][t]; reused as ww[zi][zj]
  __shared__ __align__(16) float wx[64][68];    // wx[s][z]
  __shared__ __align__(16) float tmp[64][68];   // (H@wx)[r][z]
  __shared__ float yl[64], wh[64], zv[64];
  const int b = blockIdx.x;
  const int tid = threadIdx.x;
  const float* Hb = Hm + (size_t)b*4096;
  for (int i = tid; i < 4096; i += 256) {
    Hl[i>>6][i&63] = Hb[i];
    wx[i>>6][i&63] = wxf[(size_t)b*4096 + i] + wxb[(size_t)b*4096 + i];
  }
  if (tid < 64) {
    yl[tid] = y[b*64+tid];
    zv[tid] = z0f[(size_t)b*64+tid] + z0b[(size_t)b*64+tid];
  }
  __syncthreads();
  const int zq = tid & 15, tq = tid >> 4;
  #pragma unroll
  for (int rr = 0; rr < 4; ++rr) {             // tmp = H @ wx
    const int r = 4*tq + rr;
    float4 a = make_float4(0.f,0.f,0.f,0.f);
    for (int t = 0; t < 64; ++t) fma4(a, Hl[r][t], *(const float4*)&wx[t][4*zq]);
    *(float4*)&tmp[r][4*zq] = a;
  }
  __syncthreads();                              // Hl reads done -> reuse as ww
  float (*ww)[68] = Hl;
  #pragma unroll
  for (int ii = 0; ii < 4; ++ii) {              // ww = tmp^T tmp
    const int zi = 4*tq + ii;
    float4 a = make_float4(0.f,0.f,0.f,0.f);
    for (int r = 0; r < 64; ++r) fma4(a, tmp[r][zi], *(const float4*)&tmp[r][4*zq]);
    *(float4*)&ww[zi][4*zq] = a;
  }
  if (tid < 64) {                               // wh = tmp^T y
    float acc = 0.f;
    for (int r = 0; r < 64; ++r) acc += tmp[r][tid]*yl[r];
    wh[tid] = acc;
  }
  __syncthreads();
  for (int itr = 0; itr < 10; ++itr) {          // z += 2e-6*(wh - ww@z)
    float nz = 0.f;
    if (tid < 64) {
      float mv = 0.f;
      for (int k2 = 0; k2 < 64; ++k2) mv += ww[tid][k2]*zv[k2];
      nz = zv[tid] + 2e-6f*(wh[tid] - mv);
    }
    __syncthreads();
    if (tid < 64) zv[tid] = nz;
    __syncthreads();
  }
  if (tid < 64) {                               // out = wx @ z
    float o = 0.f;
    for (int z2 = 0; z2 < 64; ++z2) o += wx[tid][z2]*zv[z2];
    out[(size_t)b*64 + tid] = o;
  }
}

// ---------------------------------------------------------------------------
extern "C" void kernel_launch(void* const* d_in, const int* in_sizes, int n_in,
                              void* d_out, int out_size, void* d_ws, size_t ws_size,
                              hipStream_t stream)
{
  const float* y    = (const float*)d_in[0];
  const float* Hm   = (const float*)d_in[1];
  const float* xraw = (const float*)d_in[2];
  const float* wih  = (const float*)d_in[3];
  const float* whh  = (const float*)d_in[4];
  const float* bih  = (const float*)d_in[5];
  const float* bhh  = (const float*)d_in[6];
  const float* Wz   = (const float*)d_in[7];
  const float* Wx   = (const float*)d_in[8];
  const float* gam  = (const float*)d_in[9];
  const float* bet  = (const float*)d_in[10];
  float* out = (float*)d_out;
  float* ws  = (float*)d_ws;

  // ws layout (floats), total = 102,419,328 floats = 409.68 MB (== round-3
  // proven footprint). No aliasing anywhere.
  float* wxf   = ws;                        // 33,554,432
  float* wxb   = wxf + 33554432ull;         // 33,554,432
  float* z0f   = wxb + 33554432ull;         // 524,288
  float* z0b   = z0f + 524288ull;           // 524,288
  float* htyU  = z0b + 524288ull;           // 524,288  [s][b] unscaled Hty
  float* rows  = htyU + 524288ull;          // 768
  float* bnacc = rows + 768ull;             // 2,048 (spaced x16)
  float* bnac  = bnacc + 2048ull;           // 128
  short* Wgs   = (short*)(bnac + 128ull);   // 294,912 shorts
  short* W2gs  = Wgs + 294912ull;           // 65,536 shorts
  short* fragX = W2gs + 65536ull;           // 67,108,864 shorts (134 MB)

  hipMemsetAsync(bnacc, 0, 2048*sizeof(float), stream);
  k_feats <<<8192, 256, 0, stream>>>(Hm, y, fragX, htyU, bnacc);
  k_prep  <<<1412, 256, 0, stream>>>(wih, whh, Wz, Wx, Wgs, W2gs, rows);
  k_bnfin <<<1, 64, 0, stream>>>(bnacc, gam, bet, bnac);
  k_scan  <<<256, 512, 0, stream>>>(fragX, htyU, xraw, Wgs, W2gs,
                                    bih, bhh, rows, bnac, wih, wxf, z0f);
  k_gd    <<<8192, 256, 0, stream>>>(Hm, y, wxf, wxb, z0f, z0b, out);
}